// Round 3
// baseline (590.860 us; speedup 1.0000x reference)
//
#include <hip/hip_runtime.h>
#include <hip/hip_bf16.h>

// MultiheadAttention (heads=1 due to reference bug): B=4, N=4096, D=512, PROJ=512.
// scale = 1/sqrt(64) = 0.125.
// Inputs fp32 (per reference; confirmed by R1 NaN when read as bf16).
// OUTPUT fp32 (reference output dtype; R2's absmax 4.13 == bf16-written-into-fp32-buffer
// signature: first half ~ out[2i+1] vs ref[i], second half zeros).
// Internally: fp32 -> bf16 at staging, MFMA bf16, fp32 accum.
//
// Pipeline (6 launches on stream):
//  1. transpose_w           Wt[n][k] (bf16) = W[k][n] (fp32) for w_q,w_k,w_v,w_mha
//  2. gemm_bt_bias<1,0,0>   qp = q @ Wq + b    (M=16384, K=512, N=512, A fp32, C bf16)
//  3. gemm_bt_bias<1,0,0>   kp = k @ Wk + b
//  4. gemm_bt_bias<1,1,0>   vpT[b][e][j] = (v @ Wv + b)[b][j][e]   (transposed epilogue)
//  5. flash_attn            dpa = softmax(qp kp^T * 0.125) @ vp  (online softmax, Tk=64)
//  6. gemm_bt_bias<0,0,1>   out = dpa @ w_mha + b_mha -> d_out (FP32)
//
// ws layout (shorts): qp, kp, vpT, dpa (8388608 each), Wt (4*262144) = 69 MB.

typedef __attribute__((ext_vector_type(8))) short bf16x8;
typedef __attribute__((ext_vector_type(4))) float f32x4;

#define NB 4
#define NN 4096
#define ND 512

__device__ __forceinline__ f32x4 mfma16(bf16x8 a, bf16x8 b, f32x4 c) {
    return __builtin_amdgcn_mfma_f32_16x16x32_bf16(a, b, c, 0, 0, 0);
}
__device__ __forceinline__ short f2bf(float f) {
    __hip_bfloat16 h = __float2bfloat16(f);
    return *reinterpret_cast<short*>(&h);
}

// ---------------- weight transpose: Wt[c][r] (bf16) = W[r][c] (fp32), 512x512 ----
struct Ptrs4 {
    const float* in[4];
    short* out[4];
};

__global__ void transpose_w(Ptrs4 p) {
    __shared__ short tile[32][33];
    const float* in = p.in[blockIdx.z];
    short* out = p.out[blockIdx.z];
    int r0 = blockIdx.y * 32, c0 = blockIdx.x * 32;
    int tx = threadIdx.x, ty = threadIdx.y;  // 32 x 8
    for (int i = 0; i < 32; i += 8)
        tile[ty + i][tx] = f2bf(in[(r0 + ty + i) * 512 + c0 + tx]);
    __syncthreads();
    for (int i = 0; i < 32; i += 8)
        out[(c0 + ty + i) * 512 + r0 + tx] = tile[tx][ty + i];
}

// ---------------- bt-form GEMM + bias: C[m][n] = sum_k A[m][k]*Bt[n][k] + bias[n] ----
// K = N = 512 fixed. 64x64 tile, 256 threads (4 waves), each wave a 32x32 quadrant.
// AF32: A operand is fp32 (converted to bf16 at staging); else bf16.
// VT:   epilogue writes per-batch transposed C_T[b][n][j] (j = m & 4095) instead of C[m][n].
// OF32: epilogue writes fp32 (d_out); else bf16 (workspace).
template <int AF32, int VT, int OF32>
__global__ __launch_bounds__(256, 4) void gemm_bt_bias(
    const void* __restrict__ Av, const short* __restrict__ Bt,
    const float* __restrict__ bias, void* __restrict__ C) {
    __shared__ short As[64][72];
    __shared__ short Bs[64][72];
    int tid = threadIdx.x;
    int lane = tid & 63, w = tid >> 6;
    int l15 = lane & 15, l4 = lane >> 4;
    int wr = (w & 1) * 32, wcn = (w >> 1) * 32;
    int m0 = blockIdx.y * 64, n0 = blockIdx.x * 64;
    f32x4 acc[4] = {};  // [mi*2+ni]
    int srow = tid >> 3, scol8 = (tid & 7) * 8;
    for (int kt = 0; kt < 512; kt += 64) {
        __syncthreads();
        for (int i = 0; i < 64; i += 32) {
            int r = srow + i;
            if (AF32) {
                const float* A = (const float*)Av;
                const float* src = &A[(size_t)(m0 + r) * 512 + kt + scol8];
                float4 f0 = *(const float4*)src;
                float4 f1 = *(const float4*)(src + 4);
                short tmp[8];
                tmp[0] = f2bf(f0.x); tmp[1] = f2bf(f0.y);
                tmp[2] = f2bf(f0.z); tmp[3] = f2bf(f0.w);
                tmp[4] = f2bf(f1.x); tmp[5] = f2bf(f1.y);
                tmp[6] = f2bf(f1.z); tmp[7] = f2bf(f1.w);
                *(bf16x8*)&As[r][scol8] = *(bf16x8*)tmp;
            } else {
                const short* A = (const short*)Av;
                *(bf16x8*)&As[r][scol8] = *(const bf16x8*)&A[(size_t)(m0 + r) * 512 + kt + scol8];
            }
            *(bf16x8*)&Bs[r][scol8] = *(const bf16x8*)&Bt[(n0 + r) * 512 + kt + scol8];
        }
        __syncthreads();
        for (int kb = 0; kb < 2; kb++) {
            int ko = kb * 32 + l4 * 8;
            bf16x8 a0 = *(const bf16x8*)&As[wr + l15][ko];
            bf16x8 a1 = *(const bf16x8*)&As[wr + 16 + l15][ko];
            bf16x8 b0 = *(const bf16x8*)&Bs[wcn + l15][ko];
            bf16x8 b1 = *(const bf16x8*)&Bs[wcn + 16 + l15][ko];
            acc[0] = mfma16(a0, b0, acc[0]);
            acc[1] = mfma16(a0, b1, acc[1]);
            acc[2] = mfma16(a1, b0, acc[2]);
            acc[3] = mfma16(a1, b1, acc[3]);
        }
    }
    for (int mi = 0; mi < 2; mi++)
        for (int ni = 0; ni < 2; ni++) {
            f32x4 vv = acc[mi * 2 + ni];
            int col = n0 + wcn + ni * 16 + l15;
            float bv = bias[col];
            for (int r = 0; r < 4; r++) {
                int row = m0 + wr + mi * 16 + l4 * 4 + r;
                float val = vv[r] + bv;
                if (VT) {
                    int b = row >> 12, j = row & 4095;
                    ((short*)C)[(size_t)b * (ND * NN) + (size_t)col * NN + j] = f2bf(val);
                } else if (OF32) {
                    ((float*)C)[(size_t)row * 512 + col] = val;
                } else {
                    ((short*)C)[(size_t)row * 512 + col] = f2bf(val);
                }
            }
        }
}

// ---------------- flash attention ----------------
// Block: 64 Q-rows of one batch, 512 threads (8 waves). Online softmax over 64-key
// chunks. Q frags persistent in regs (16 x bf16x8). O accum 16 x f32x4 per lane.
__global__ __launch_bounds__(512, 2) void flash_attn(
    const short* __restrict__ qp, const short* __restrict__ kp,
    const short* __restrict__ vpT, short* __restrict__ dpa) {
    __shared__ short stage[18432];      // union: kp half [64][264] / vpT half [256][72]
    __shared__ float Sld[64][66];
    __shared__ short Pld[64][72];
    __shared__ float mrow[64], lrow[64], arow[64];

    int tid = threadIdx.x;
    int lane = tid & 63, w = tid >> 6;
    int l15 = lane & 15, l4 = lane >> 4;
    int wr = w & 3;    // row block (16 rows)
    int wc = w >> 2;   // 0/1
    int b = blockIdx.y;
    int q0 = blockIdx.x * 64;

    const short* qpb = qp + b * (NN * ND);
    const short* kpb = kp + b * (NN * ND);
    const short* vtb = vpT + b * (ND * NN);

    // persistent Q fragments: rows q0 + 16*wr + l15, k = kb*32 + l4*8
    bf16x8 qf[16];
    {
        const short* qrow = qpb + (q0 + wr * 16 + l15) * ND + l4 * 8;
#pragma unroll
        for (int kb = 0; kb < 16; kb++) qf[kb] = *(const bf16x8*)(qrow + kb * 32);
    }
    f32x4 oacc[16] = {};
    if (tid < 64) { mrow[tid] = -1e30f; lrow[tid] = 0.f; }

    for (int j0 = 0; j0 < NN; j0 += 64) {
        // ---- S = Q K^T (two k-halves staged) ----
        f32x4 sacc[2] = {};
        for (int kh = 0; kh < 2; kh++) {
            __syncthreads();
            {
                int key = tid >> 5;
                int c8 = (tid & 31) * 8;
#pragma unroll
                for (int i = 0; i < 64; i += 16)
                    *(bf16x8*)&stage[(key + i) * 264 + c8] =
                        *(const bf16x8*)&kpb[(j0 + key + i) * ND + kh * 256 + c8];
            }
            __syncthreads();
            int ko = l4 * 8;
#pragma unroll
            for (int i = 0; i < 8; i++) {
                bf16x8 b0 = *(const bf16x8*)&stage[(32 * wc + l15) * 264 + i * 32 + ko];
                bf16x8 b1 = *(const bf16x8*)&stage[(32 * wc + 16 + l15) * 264 + i * 32 + ko];
                sacc[0] = mfma16(qf[kh * 8 + i], b0, sacc[0]);
                sacc[1] = mfma16(qf[kh * 8 + i], b1, sacc[1]);
            }
        }
        // write scaled S to LDS
#pragma unroll
        for (int c = 0; c < 2; c++)
#pragma unroll
            for (int r = 0; r < 4; r++)
                Sld[wr * 16 + l4 * 4 + r][wc * 32 + c * 16 + l15] = sacc[c][r] * 0.125f;
        __syncthreads();
        // ---- online softmax: 8 threads per row ----
        {
            int row = tid >> 3, c8 = tid & 7;
            float v[8];
            float mx = -1e30f;
#pragma unroll
            for (int i = 0; i < 8; i++) { v[i] = Sld[row][c8 * 8 + i]; mx = fmaxf(mx, v[i]); }
#pragma unroll
            for (int off = 1; off < 8; off <<= 1) mx = fmaxf(mx, __shfl_xor(mx, off));
            float mo = mrow[row];
            float mn = fmaxf(mo, mx);
            float ps = 0.f;
#pragma unroll
            for (int i = 0; i < 8; i++) { v[i] = __expf(v[i] - mn); ps += v[i]; }
#pragma unroll
            for (int off = 1; off < 8; off <<= 1) ps += __shfl_xor(ps, off);
            float al = __expf(mo - mn);
            if (c8 == 0) { mrow[row] = mn; lrow[row] = lrow[row] * al + ps; arow[row] = al; }
#pragma unroll
            for (int i = 0; i < 8; i++) Pld[row][c8 * 8 + i] = f2bf(v[i]);
        }
        __syncthreads();
        // ---- rescale O by alpha, load P frags ----
        float al4[4];
#pragma unroll
        for (int r = 0; r < 4; r++) al4[r] = arow[wr * 16 + l4 * 4 + r];
#pragma unroll
        for (int t = 0; t < 16; t++)
#pragma unroll
            for (int r = 0; r < 4; r++) oacc[t][r] *= al4[r];
        bf16x8 pa0 = *(const bf16x8*)&Pld[wr * 16 + l15][l4 * 8];
        bf16x8 pa1 = *(const bf16x8*)&Pld[wr * 16 + l15][32 + l4 * 8];
        // ---- O += P V (two e-halves staged) ----
        for (int eh = 0; eh < 2; eh++) {
            __syncthreads();
            {
                int e = tid >> 3;
                int c8 = (tid & 7) * 8;
#pragma unroll
                for (int i = 0; i < 256; i += 64)
                    *(bf16x8*)&stage[(e + i) * 72 + c8] =
                        *(const bf16x8*)&vtb[(eh * 256 + e + i) * NN + j0 + c8];
            }
            __syncthreads();
#pragma unroll
            for (int i = 0; i < 8; i++) {
                int ep = 32 * i + 16 * wc + l15;  // LDS e-row; global col tile ct=16*eh+2*i+wc
                bf16x8 b0 = *(const bf16x8*)&stage[ep * 72 + l4 * 8];
                bf16x8 b1 = *(const bf16x8*)&stage[ep * 72 + 32 + l4 * 8];
                int oi = eh * 8 + i;
                oacc[oi] = mfma16(pa0, b0, oacc[oi]);
                oacc[oi] = mfma16(pa1, b1, oacc[oi]);
            }
        }
    }
    __syncthreads();
    // ---- finalize: O /= l, store dpa ----
    float li[4];
#pragma unroll
    for (int r = 0; r < 4; r++) li[r] = 1.f / lrow[wr * 16 + l4 * 4 + r];
    short* dpb = dpa + b * (NN * ND);
#pragma unroll
    for (int eh = 0; eh < 2; eh++)
#pragma unroll
        for (int i = 0; i < 8; i++) {
            int ct = 16 * eh + 2 * i + wc;
            int col = ct * 16 + l15;
#pragma unroll
            for (int r = 0; r < 4; r++) {
                int row = q0 + wr * 16 + l4 * 4 + r;
                dpb[row * ND + col] = f2bf(oacc[eh * 8 + i][r] * li[r]);
            }
        }
}

extern "C" void kernel_launch(void* const* d_in, const int* in_sizes, int n_in,
                              void* d_out, int out_size, void* d_ws, size_t ws_size,
                              hipStream_t stream) {
    const float* q     = (const float*)d_in[0];
    const float* k     = (const float*)d_in[1];
    const float* v     = (const float*)d_in[2];
    const float* w_q   = (const float*)d_in[3];
    const float* w_k   = (const float*)d_in[4];
    const float* w_v   = (const float*)d_in[5];
    const float* w_mha = (const float*)d_in[6];
    const float* b_q   = (const float*)d_in[7];
    const float* b_k   = (const float*)d_in[8];
    const float* b_v   = (const float*)d_in[9];
    const float* b_mha = (const float*)d_in[10];

    const size_t T = (size_t)NB * NN * ND;  // 8388608
    short* ws  = (short*)d_ws;
    short* qp  = ws;
    short* kp  = qp + T;
    short* vpT = kp + T;
    short* dpa = vpT + T;
    short* Wt  = dpa + T;  // 4 * 262144 shorts

    Ptrs4 p;
    p.in[0] = w_q;   p.out[0] = Wt;
    p.in[1] = w_k;   p.out[1] = Wt + 262144;
    p.in[2] = w_v;   p.out[2] = Wt + 524288;
    p.in[3] = w_mha; p.out[3] = Wt + 786432;
    transpose_w<<<dim3(16, 16, 4), dim3(32, 8), 0, stream>>>(p);

    gemm_bt_bias<1, 0, 0><<<dim3(8, 256), 256, 0, stream>>>(q, Wt,          b_q, qp);
    gemm_bt_bias<1, 0, 0><<<dim3(8, 256), 256, 0, stream>>>(k, Wt + 262144, b_k, kp);
    gemm_bt_bias<1, 1, 0><<<dim3(8, 256), 256, 0, stream>>>(v, Wt + 524288, b_v, vpT);

    flash_attn<<<dim3(64, 4), 512, 0, stream>>>(qp, kp, vpT, dpa);

    gemm_bt_bias<0, 0, 1><<<dim3(8, 256), 256, 0, stream>>>(dpa, Wt + 786432, b_mha, d_out);
}